// Round 3
// baseline (998.425 us; speedup 1.0000x reference)
//
#include <hip/hip_runtime.h>

#define N_NODES 100000
#define F 64

// One edge per wave, lane = feature channel.
// gather x[src]*w, atomically accumulate into agg[dst].
__global__ void scatter_kernel(const float* __restrict__ xin,
                               const int* __restrict__ src,
                               const int* __restrict__ dst,
                               const float* __restrict__ ew,
                               float* __restrict__ agg,
                               int E) {
    int gid  = blockIdx.x * blockDim.x + threadIdx.x;
    int eid  = gid >> 6;
    int lane = threadIdx.x & 63;
    if (eid >= E) return;
    int   s = src[eid];          // wave-uniform address -> single coalesced req
    int   d = dst[eid];
    float w = ew[eid];
    float v = w * xin[(size_t)s * F + lane];   // coalesced 256B gather per wave
    atomicAdd(&agg[(size_t)d * F + lane], v);  // 64 consecutive floats
}

// out[n,:] = agg[n,:] @ Wrel + bias + xroot[n,:] @ Wroot   (optional ReLU)
// One wave per node row; lane = output channel; weights staged in LDS.
template <bool RELU>
__global__ void dense_kernel(const float* __restrict__ agg,
                             const float* __restrict__ xroot,
                             const float* __restrict__ Wrel,
                             const float* __restrict__ Wroot,
                             const float* __restrict__ bias,
                             float* __restrict__ out) {
    __shared__ float Wr[F * F];   // 16 KiB
    __shared__ float Wo[F * F];   // 16 KiB
    for (int i = threadIdx.x; i < F * F; i += blockDim.x) {
        Wr[i] = Wrel[i];
        Wo[i] = Wroot[i];
    }
    __syncthreads();

    const int lane       = threadIdx.x & 63;
    const int wavesPerBk = blockDim.x >> 6;
    const int gwave      = blockIdx.x * wavesPerBk + (threadIdx.x >> 6);
    const int totalWaves = gridDim.x * wavesPerBk;
    const float b = bias[lane];

    for (int n = gwave; n < N_NODES; n += totalWaves) {
        const float* __restrict__ arow = agg   + (size_t)n * F;
        const float* __restrict__ xrow = xroot + (size_t)n * F;
        float acc = b;
#pragma unroll 8
        for (int k = 0; k < F; ++k) {
            // arow[k]/xrow[k]: wave-uniform broadcast loads (L1-hit)
            // Wr[k*64+lane]: lanes hit banks lane%32 -> 2-way alias, free
            acc += arow[k] * Wr[k * F + lane];
            acc += xrow[k] * Wo[k * F + lane];
        }
        if (RELU) acc = fmaxf(acc, 0.0f);
        out[(size_t)n * F + lane] = acc;  // in-place vs xroot is safe per-row
    }
}

extern "C" void kernel_launch(void* const* d_in, const int* in_sizes, int n_in,
                              void* d_out, int out_size, void* d_ws, size_t ws_size,
                              hipStream_t stream) {
    const float* x   = (const float*)d_in[0];
    const int*   ei  = (const int*)d_in[1];   // [2, E] int32
    const float* ew  = (const float*)d_in[2];
    const float* W1r = (const float*)d_in[3];
    const float* b1  = (const float*)d_in[4];
    const float* W1o = (const float*)d_in[5];
    const float* W2r = (const float*)d_in[6];
    const float* b2  = (const float*)d_in[7];
    const float* W2o = (const float*)d_in[8];
    float*       out = (float*)d_out;

    const int E = in_sizes[2];          // edge_weight element count
    const int* src = ei;                // row 0
    const int* dst = ei + E;            // row 1

    const size_t aggBytes = (size_t)N_NODES * F * sizeof(float);
    float* agg = (float*)d_ws;
    float* h   = (ws_size >= 2 * aggBytes)
               ? (float*)((char*)d_ws + aggBytes)
               : out;  // in-place fallback, safe per analysis above

    const int scatterBlocks = (int)(((long long)E * 64 + 255) / 256);
    const int denseBlocks   = 1024;   // 4 blocks/CU, 128 KiB LDS/CU

    // ---- layer 1 ----
    hipMemsetAsync(agg, 0, aggBytes, stream);
    scatter_kernel<<<scatterBlocks, 256, 0, stream>>>(x, src, dst, ew, agg, E);
    dense_kernel<true><<<denseBlocks, 256, 0, stream>>>(agg, x, W1r, W1o, b1, h);

    // ---- layer 2 ----
    hipMemsetAsync(agg, 0, aggBytes, stream);
    scatter_kernel<<<scatterBlocks, 256, 0, stream>>>(h, src, dst, ew, agg, E);
    dense_kernel<false><<<denseBlocks, 256, 0, stream>>>(agg, h, W2r, W2o, b2, out);
}

// Round 5
// 536.615 us; speedup vs baseline: 1.8606x; 1.8606x over previous
//
#include <hip/hip_runtime.h>

#define N_NODES 100000
#define F 64
#define SCAN_TPB 256
#define SCAN_ELEMS 1024

// ---------------- CSR build ----------------
__global__ void hist_kernel(const int* __restrict__ dst, int* __restrict__ cnt, int E) {
    int i = blockIdx.x * blockDim.x + threadIdx.x;
    if (i < E) atomicAdd(&cnt[dst[i]], 1);
}

__global__ void scan1_kernel(const int* __restrict__ cnt, int* __restrict__ excl,
                             int* __restrict__ bsum, int n) {
    __shared__ int sh[SCAN_TPB];
    const int t = threadIdx.x;
    const int base = blockIdx.x * SCAN_ELEMS + t * 4;
    int v0 = (base + 0 < n) ? cnt[base + 0] : 0;
    int v1 = (base + 1 < n) ? cnt[base + 1] : 0;
    int v2 = (base + 2 < n) ? cnt[base + 2] : 0;
    int v3 = (base + 3 < n) ? cnt[base + 3] : 0;
    const int tot = v0 + v1 + v2 + v3;
    sh[t] = tot; __syncthreads();
    for (int off = 1; off < SCAN_TPB; off <<= 1) {
        int x = (t >= off) ? sh[t - off] : 0;
        __syncthreads();
        sh[t] += x;
        __syncthreads();
    }
    int exc = sh[t] - tot;
    if (t == SCAN_TPB - 1) bsum[blockIdx.x] = sh[t];
    if (base + 0 < n) excl[base + 0] = exc;  exc += v0;
    if (base + 1 < n) excl[base + 1] = exc;  exc += v1;
    if (base + 2 < n) excl[base + 2] = exc;  exc += v2;
    if (base + 3 < n) excl[base + 3] = exc;
}

__global__ void scan2_kernel(int* __restrict__ bsum, int nb) {
    __shared__ int sh[SCAN_TPB];
    const int t = threadIdx.x;
    const int v = (t < nb) ? bsum[t] : 0;
    sh[t] = v; __syncthreads();
    for (int off = 1; off < SCAN_TPB; off <<= 1) {
        int x = (t >= off) ? sh[t - off] : 0;
        __syncthreads();
        sh[t] += x;
        __syncthreads();
    }
    if (t < nb) bsum[t] = sh[t] - v;   // exclusive
}

__global__ void scan3_kernel(int* __restrict__ excl, const int* __restrict__ bsum,
                             int n, int E) {
    int i = blockIdx.x * blockDim.x + threadIdx.x;
    if (i < n) excl[i] += bsum[i / SCAN_ELEMS];
    if (i == 0) excl[n] = E;   // rowptr[N] = E
}

__global__ void reorder_kernel(const int* __restrict__ src, const int* __restrict__ dst,
                               const float* __restrict__ ew, int* __restrict__ cursor,
                               int* __restrict__ eSrc, float* __restrict__ eW, int E) {
    int i = blockIdx.x * blockDim.x + threadIdx.x;
    if (i >= E) return;
    int d = dst[i];
    int pos = atomicAdd(&cursor[d], 1);
    eSrc[pos] = src[i];
    eW[pos]   = ew[i];
}

// ---------------- aggregation: gather per node (no atomics) ----------------
__global__ void gather_kernel(const float* __restrict__ xin, const int* __restrict__ rowptr,
                              const int* __restrict__ eSrc, const float* __restrict__ eW,
                              float* __restrict__ agg) {
    const int wid  = (blockIdx.x * blockDim.x + threadIdx.x) >> 6;  // node id
    const int lane = threadIdx.x & 63;
    if (wid >= N_NODES) return;
    int beg = __builtin_amdgcn_readfirstlane(rowptr[wid]);
    int end = __builtin_amdgcn_readfirstlane(rowptr[wid + 1]);
    float acc = 0.f;
    int e = beg;
    for (; e + 2 <= end; e += 2) {                       // 2-deep ILP
        int   s0 = eSrc[e],   s1 = eSrc[e + 1];
        float w0 = eW[e],     w1 = eW[e + 1];
        acc += w0 * xin[(size_t)s0 * F + lane];          // coalesced 256B row gather
        acc += w1 * xin[(size_t)s1 * F + lane];
    }
    if (e < end) acc += eW[e] * xin[(size_t)eSrc[e] * F + lane];
    agg[(size_t)wid * F + lane] = acc;                   // single plain store
}

// ---------------- legacy atomic scatter (fallback if ws too small) ----------------
__global__ void scatter_kernel(const float* __restrict__ xin,
                               const int* __restrict__ src,
                               const int* __restrict__ dst,
                               const float* __restrict__ ew,
                               float* __restrict__ agg, int E) {
    int gid  = blockIdx.x * blockDim.x + threadIdx.x;
    int eid  = gid >> 6;
    int lane = threadIdx.x & 63;
    if (eid >= E) return;
    float v = ew[eid] * xin[(size_t)src[eid] * F + lane];
    atomicAdd(&agg[(size_t)dst[eid] * F + lane], v);
}

// ---------------- dense: out = A@Wrel + b + X@Wroot, tiled ----------------
// 64-row tile per block, 256 threads = 16 row-groups x 16 col-groups, 4x4 micro-tile.
// sA/sX XOR-swizzled (A[r][k] at r*64 + (k ^ (r&31))) -> conflict-free column reads.
template <bool RELU>
__global__ void dense_tiled(const float* __restrict__ A,
                            const float* __restrict__ X,
                            const float* __restrict__ Wrel,
                            const float* __restrict__ Wroot,
                            const float* __restrict__ bias,
                            float* __restrict__ out) {
    __shared__ float sWr[F * F];
    __shared__ float sWo[F * F];
    __shared__ float sA[F * F];
    __shared__ float sX[F * F];

    const int t = threadIdx.x;
    for (int i = t; i < 1024; i += 256) {   // weights, row-major [k][c]
        reinterpret_cast<float4*>(sWr)[i] = reinterpret_cast<const float4*>(Wrel)[i];
        reinterpret_cast<float4*>(sWo)[i] = reinterpret_cast<const float4*>(Wroot)[i];
    }

    const int row0 = blockIdx.x * 64;
    for (int i = t; i < 1024; i += 256) {   // A,X tiles, swizzled
        const int r  = i >> 4;
        const int c4 = (i & 15) << 2;
        int rr = row0 + r; if (rr > N_NODES - 1) rr = N_NODES - 1;   // tail clamp (own rows)
        const float4 av = *reinterpret_cast<const float4*>(A + (size_t)rr * F + c4);
        const float4 xv = *reinterpret_cast<const float4*>(X + (size_t)rr * F + c4);
        const int rbase = r * F, rx = r & 31;
        sA[rbase + ((c4 + 0) ^ rx)] = av.x;
        sA[rbase + ((c4 + 1) ^ rx)] = av.y;
        sA[rbase + ((c4 + 2) ^ rx)] = av.z;
        sA[rbase + ((c4 + 3) ^ rx)] = av.w;
        sX[rbase + ((c4 + 0) ^ rx)] = xv.x;
        sX[rbase + ((c4 + 1) ^ rx)] = xv.y;
        sX[rbase + ((c4 + 2) ^ rx)] = xv.z;
        sX[rbase + ((c4 + 3) ^ rx)] = xv.w;
    }
    __syncthreads();

    const int cg = (t & 15) << 2;
    const int rg = (t >> 4) << 2;
    float acc[4][4];
    {
        const float b0 = bias[cg], b1 = bias[cg + 1], b2 = bias[cg + 2], b3 = bias[cg + 3];
#pragma unroll
        for (int i = 0; i < 4; ++i) { acc[i][0] = b0; acc[i][1] = b1; acc[i][2] = b2; acc[i][3] = b3; }
    }
    int rbase[4], rxs[4];
#pragma unroll
    for (int i = 0; i < 4; ++i) { rbase[i] = (rg + i) * F; rxs[i] = (rg + i) & 31; }

#pragma unroll 4
    for (int k = 0; k < F; ++k) {
        const float4 wr = *reinterpret_cast<const float4*>(&sWr[k * F + cg]);
        const float4 wo = *reinterpret_cast<const float4*>(&sWo[k * F + cg]);
#pragma unroll
        for (int i = 0; i < 4; ++i) {
            const float a  = sA[rbase[i] + (k ^ rxs[i])];
            const float xv = sX[rbase[i] + (k ^ rxs[i])];
            acc[i][0] += a * wr.x + xv * wo.x;
            acc[i][1] += a * wr.y + xv * wo.y;
            acc[i][2] += a * wr.z + xv * wo.z;
            acc[i][3] += a * wr.w + xv * wo.w;
        }
    }

#pragma unroll
    for (int i = 0; i < 4; ++i) {
        const int n = row0 + rg + i;
        if (n < N_NODES) {
            float4 o;
            o.x = acc[i][0]; o.y = acc[i][1]; o.z = acc[i][2]; o.w = acc[i][3];
            if (RELU) {
                o.x = fmaxf(o.x, 0.f); o.y = fmaxf(o.y, 0.f);
                o.z = fmaxf(o.z, 0.f); o.w = fmaxf(o.w, 0.f);
            }
            *reinterpret_cast<float4*>(out + (size_t)n * F + cg) = o;
        }
    }
}

extern "C" void kernel_launch(void* const* d_in, const int* in_sizes, int n_in,
                              void* d_out, int out_size, void* d_ws, size_t ws_size,
                              hipStream_t stream) {
    const float* x   = (const float*)d_in[0];
    const int*   ei  = (const int*)d_in[1];
    const float* ew  = (const float*)d_in[2];
    const float* W1r = (const float*)d_in[3];
    const float* b1  = (const float*)d_in[4];
    const float* W1o = (const float*)d_in[5];
    const float* W2r = (const float*)d_in[6];
    const float* b2  = (const float*)d_in[7];
    const float* W2o = (const float*)d_in[8];
    float*       out = (float*)d_out;

    const int E = in_sizes[2];
    const int* src = ei;
    const int* dst = ei + E;

    const int nScanBlocks = (N_NODES + SCAN_ELEMS - 1) / SCAN_ELEMS;   // 98
    const size_t aggB = (size_t)N_NODES * F * sizeof(float);           // 25.6 MB
    const size_t eB   = (size_t)E * 4;                                 // 6.4 MB
    const size_t rpB  = (((size_t)(N_NODES + 1) * 4) + 15) & ~(size_t)15;
    const size_t curB = (((size_t)N_NODES * 4) + 15) & ~(size_t)15;
    const size_t bsB  = (((size_t)nScanBlocks * 4) + 15) & ~(size_t)15;

    char* p = (char*)d_ws;
    float* agg    = (float*)p;  p += aggB;
    int*   eSrc   = (int*)p;    p += eB;
    float* eWgt   = (float*)p;  p += eB;
    int*   rowptr = (int*)p;    p += rpB;
    int*   cursor = (int*)p;    p += curB;
    int*   bsum   = (int*)p;    p += bsB;
    const size_t need = (size_t)(p - (char*)d_ws);

    const int denseBlocks  = (N_NODES + 63) / 64;          // 1563
    const int gatherBlocks = (N_NODES * 64) / 256;         // 25000

    if (ws_size >= need) {
        // ---- CSR build (once, reused by both layers) ----
        hipMemsetAsync(cursor, 0, (size_t)N_NODES * 4, stream);          // counts
        hist_kernel<<<(E + 255) / 256, 256, 0, stream>>>(dst, cursor, E);
        scan1_kernel<<<nScanBlocks, SCAN_TPB, 0, stream>>>(cursor, rowptr, bsum, N_NODES);
        scan2_kernel<<<1, SCAN_TPB, 0, stream>>>(bsum, nScanBlocks);
        scan3_kernel<<<(N_NODES + 255) / 256, 256, 0, stream>>>(rowptr, bsum, N_NODES, E);
        hipMemcpyAsync(cursor, rowptr, (size_t)N_NODES * 4, hipMemcpyDeviceToDevice, stream);
        reorder_kernel<<<(E + 255) / 256, 256, 0, stream>>>(src, dst, ew, cursor, eSrc, eWgt, E);

        // ---- layer 1: agg = scatter(x); h(out) = dense(agg, x) ----
        gather_kernel<<<gatherBlocks, 256, 0, stream>>>(x, rowptr, eSrc, eWgt, agg);
        dense_tiled<true><<<denseBlocks, 256, 0, stream>>>(agg, x, W1r, W1o, b1, out);

        // ---- layer 2: agg = scatter(h); out = dense(agg, h) (in-place safe) ----
        gather_kernel<<<gatherBlocks, 256, 0, stream>>>(out, rowptr, eSrc, eWgt, agg);
        dense_tiled<false><<<denseBlocks, 256, 0, stream>>>(agg, out, W2r, W2o, b2, out);
    } else {
        // ---- legacy atomic path (needs only agg) ----
        const int scatterBlocks = (int)(((long long)E * 64 + 255) / 256);
        hipMemsetAsync(agg, 0, aggB, stream);
        scatter_kernel<<<scatterBlocks, 256, 0, stream>>>(x, src, dst, ew, agg, E);
        dense_tiled<true><<<denseBlocks, 256, 0, stream>>>(agg, x, W1r, W1o, b1, out);
        hipMemsetAsync(agg, 0, aggB, stream);
        scatter_kernel<<<scatterBlocks, 256, 0, stream>>>(out, src, dst, ew, agg, E);
        dense_tiled<false><<<denseBlocks, 256, 0, stream>>>(agg, out, W2r, W2o, b2, out);
    }
}

// Round 6
// 519.149 us; speedup vs baseline: 1.9232x; 1.0336x over previous
//
#include <hip/hip_runtime.h>

#define N_NODES 100000
#define F 64
#define SCAN_TPB 256
#define SCAN_ELEMS 1024

// ---------------- CSR build ----------------
__global__ void hist_kernel(const int* __restrict__ dst, int* __restrict__ cnt, int E) {
    int i = blockIdx.x * blockDim.x + threadIdx.x;
    if (i < E) atomicAdd(&cnt[dst[i]], 1);
}

__global__ void scan1_kernel(const int* __restrict__ cnt, int* __restrict__ excl,
                             int* __restrict__ bsum, int n) {
    __shared__ int sh[SCAN_TPB];
    const int t = threadIdx.x;
    const int base = blockIdx.x * SCAN_ELEMS + t * 4;
    int v0 = (base + 0 < n) ? cnt[base + 0] : 0;
    int v1 = (base + 1 < n) ? cnt[base + 1] : 0;
    int v2 = (base + 2 < n) ? cnt[base + 2] : 0;
    int v3 = (base + 3 < n) ? cnt[base + 3] : 0;
    const int tot = v0 + v1 + v2 + v3;
    sh[t] = tot; __syncthreads();
    for (int off = 1; off < SCAN_TPB; off <<= 1) {
        int x = (t >= off) ? sh[t - off] : 0;
        __syncthreads();
        sh[t] += x;
        __syncthreads();
    }
    int exc = sh[t] - tot;
    if (t == SCAN_TPB - 1) bsum[blockIdx.x] = sh[t];
    if (base + 0 < n) excl[base + 0] = exc;  exc += v0;
    if (base + 1 < n) excl[base + 1] = exc;  exc += v1;
    if (base + 2 < n) excl[base + 2] = exc;  exc += v2;
    if (base + 3 < n) excl[base + 3] = exc;
}

__global__ void scan2_kernel(int* __restrict__ bsum, int nb) {
    __shared__ int sh[SCAN_TPB];
    const int t = threadIdx.x;
    const int v = (t < nb) ? bsum[t] : 0;
    sh[t] = v; __syncthreads();
    for (int off = 1; off < SCAN_TPB; off <<= 1) {
        int x = (t >= off) ? sh[t - off] : 0;
        __syncthreads();
        sh[t] += x;
        __syncthreads();
    }
    if (t < nb) bsum[t] = sh[t] - v;   // exclusive
}

__global__ void scan3_kernel(int* __restrict__ excl, const int* __restrict__ bsum,
                             int n, int E) {
    int i = blockIdx.x * blockDim.x + threadIdx.x;
    if (i < n) excl[i] += bsum[i / SCAN_ELEMS];
    if (i == 0) excl[n] = E;   // rowptr[N] = E
}

// single packed 8B scatter per edge: halves randomly-touched cache lines
__global__ void reorder_kernel(const int* __restrict__ src, const int* __restrict__ dst,
                               const float* __restrict__ ew, int* __restrict__ cursor,
                               int2* __restrict__ ePair, int E) {
    int i = blockIdx.x * blockDim.x + threadIdx.x;
    if (i >= E) return;
    int d = dst[i];
    int pos = atomicAdd(&cursor[d], 1);
    ePair[pos] = make_int2(src[i], __float_as_int(ew[i]));
}

// ---------------- aggregation: gather per node (no atomics) ----------------
__global__ void gather_kernel(const float* __restrict__ xin, const int* __restrict__ rowptr,
                              const int2* __restrict__ ePair, float* __restrict__ agg) {
    const int wid  = (blockIdx.x * blockDim.x + threadIdx.x) >> 6;  // node id
    const int lane = threadIdx.x & 63;
    if (wid >= N_NODES) return;
    int beg = __builtin_amdgcn_readfirstlane(rowptr[wid]);
    int end = __builtin_amdgcn_readfirstlane(rowptr[wid + 1]);
    float a0 = 0.f, a1 = 0.f, a2 = 0.f, a3 = 0.f;
    int e = beg;
    for (; e + 4 <= end; e += 4) {                      // 4 outstanding row fetches
        const int2 p0 = ePair[e + 0];
        const int2 p1 = ePair[e + 1];
        const int2 p2 = ePair[e + 2];
        const int2 p3 = ePair[e + 3];
        a0 += __int_as_float(p0.y) * xin[(size_t)p0.x * F + lane];
        a1 += __int_as_float(p1.y) * xin[(size_t)p1.x * F + lane];
        a2 += __int_as_float(p2.y) * xin[(size_t)p2.x * F + lane];
        a3 += __int_as_float(p3.y) * xin[(size_t)p3.x * F + lane];
    }
    for (; e < end; ++e) {
        const int2 p = ePair[e];
        a0 += __int_as_float(p.y) * xin[(size_t)p.x * F + lane];
    }
    agg[(size_t)wid * F + lane] = (a0 + a1) + (a2 + a3);
}

// ---------------- dense: out = A@Wrel + b + X@Wroot, tiled ----------------
template <bool RELU>
__global__ void dense_tiled(const float* __restrict__ A,
                            const float* __restrict__ X,
                            const float* __restrict__ Wrel,
                            const float* __restrict__ Wroot,
                            const float* __restrict__ bias,
                            float* __restrict__ out) {
    __shared__ float sWr[F * F];
    __shared__ float sWo[F * F];
    __shared__ float sA[F * F];
    __shared__ float sX[F * F];

    const int t = threadIdx.x;
    for (int i = t; i < 1024; i += 256) {   // weights, row-major [k][c]
        reinterpret_cast<float4*>(sWr)[i] = reinterpret_cast<const float4*>(Wrel)[i];
        reinterpret_cast<float4*>(sWo)[i] = reinterpret_cast<const float4*>(Wroot)[i];
    }

    const int row0 = blockIdx.x * 64;
    for (int i = t; i < 1024; i += 256) {   // A,X tiles, XOR-swizzled
        const int r  = i >> 4;
        const int c4 = (i & 15) << 2;
        int rr = row0 + r; if (rr > N_NODES - 1) rr = N_NODES - 1;   // tail clamp
        const float4 av = *reinterpret_cast<const float4*>(A + (size_t)rr * F + c4);
        const float4 xv = *reinterpret_cast<const float4*>(X + (size_t)rr * F + c4);
        const int rbase = r * F, rx = r & 31;
        sA[rbase + ((c4 + 0) ^ rx)] = av.x;
        sA[rbase + ((c4 + 1) ^ rx)] = av.y;
        sA[rbase + ((c4 + 2) ^ rx)] = av.z;
        sA[rbase + ((c4 + 3) ^ rx)] = av.w;
        sX[rbase + ((c4 + 0) ^ rx)] = xv.x;
        sX[rbase + ((c4 + 1) ^ rx)] = xv.y;
        sX[rbase + ((c4 + 2) ^ rx)] = xv.z;
        sX[rbase + ((c4 + 3) ^ rx)] = xv.w;
    }
    __syncthreads();

    const int cg = (t & 15) << 2;
    const int rg = (t >> 4) << 2;
    float acc[4][4];
    {
        const float b0 = bias[cg], b1 = bias[cg + 1], b2 = bias[cg + 2], b3 = bias[cg + 3];
#pragma unroll
        for (int i = 0; i < 4; ++i) { acc[i][0] = b0; acc[i][1] = b1; acc[i][2] = b2; acc[i][3] = b3; }
    }
    int rbase[4], rxs[4];
#pragma unroll
    for (int i = 0; i < 4; ++i) { rbase[i] = (rg + i) * F; rxs[i] = (rg + i) & 31; }

#pragma unroll 4
    for (int k = 0; k < F; ++k) {
        const float4 wr = *reinterpret_cast<const float4*>(&sWr[k * F + cg]);
        const float4 wo = *reinterpret_cast<const float4*>(&sWo[k * F + cg]);
#pragma unroll
        for (int i = 0; i < 4; ++i) {
            const float a  = sA[rbase[i] + (k ^ rxs[i])];
            const float xv = sX[rbase[i] + (k ^ rxs[i])];
            acc[i][0] += a * wr.x + xv * wo.x;
            acc[i][1] += a * wr.y + xv * wo.y;
            acc[i][2] += a * wr.z + xv * wo.z;
            acc[i][3] += a * wr.w + xv * wo.w;
        }
    }

#pragma unroll
    for (int i = 0; i < 4; ++i) {
        const int n = row0 + rg + i;
        if (n < N_NODES) {
            float4 o;
            o.x = acc[i][0]; o.y = acc[i][1]; o.z = acc[i][2]; o.w = acc[i][3];
            if (RELU) {
                o.x = fmaxf(o.x, 0.f); o.y = fmaxf(o.y, 0.f);
                o.z = fmaxf(o.z, 0.f); o.w = fmaxf(o.w, 0.f);
            }
            *reinterpret_cast<float4*>(out + (size_t)n * F + cg) = o;
        }
    }
}

// ---------------- legacy atomic scatter (fallback if ws too small) ----------------
__global__ void scatter_kernel(const float* __restrict__ xin,
                               const int* __restrict__ src,
                               const int* __restrict__ dst,
                               const float* __restrict__ ew,
                               float* __restrict__ agg, int E) {
    int gid  = blockIdx.x * blockDim.x + threadIdx.x;
    int eid  = gid >> 6;
    int lane = threadIdx.x & 63;
    if (eid >= E) return;
    float v = ew[eid] * xin[(size_t)src[eid] * F + lane];
    atomicAdd(&agg[(size_t)dst[eid] * F + lane], v);
}

extern "C" void kernel_launch(void* const* d_in, const int* in_sizes, int n_in,
                              void* d_out, int out_size, void* d_ws, size_t ws_size,
                              hipStream_t stream) {
    const float* x   = (const float*)d_in[0];
    const int*   ei  = (const int*)d_in[1];
    const float* ew  = (const float*)d_in[2];
    const float* W1r = (const float*)d_in[3];
    const float* b1  = (const float*)d_in[4];
    const float* W1o = (const float*)d_in[5];
    const float* W2r = (const float*)d_in[6];
    const float* b2  = (const float*)d_in[7];
    const float* W2o = (const float*)d_in[8];
    float*       out = (float*)d_out;

    const int E = in_sizes[2];
    const int* src = ei;
    const int* dst = ei + E;

    const int nScanBlocks = (N_NODES + SCAN_ELEMS - 1) / SCAN_ELEMS;   // 98
    const size_t aggB = (size_t)N_NODES * F * sizeof(float);           // 25.6 MB
    const size_t ePB  = (size_t)E * 8;                                 // 12.8 MB
    const size_t rpB  = (((size_t)(N_NODES + 1) * 4) + 15) & ~(size_t)15;
    const size_t curB = (((size_t)N_NODES * 4) + 15) & ~(size_t)15;
    const size_t bsB  = (((size_t)nScanBlocks * 4) + 15) & ~(size_t)15;

    char* p = (char*)d_ws;
    float* agg    = (float*)p;  p += aggB;
    int2*  ePair  = (int2*)p;   p += ePB;
    int*   rowptr = (int*)p;    p += rpB;
    int*   cursor = (int*)p;    p += curB;
    int*   bsum   = (int*)p;    p += bsB;
    const size_t need = (size_t)(p - (char*)d_ws);

    const int denseBlocks  = (N_NODES + 63) / 64;          // 1563
    const int gatherBlocks = (N_NODES * 64) / 256;         // 25000

    if (ws_size >= need) {
        // ---- CSR build (once, reused by both layers) ----
        hipMemsetAsync(cursor, 0, (size_t)N_NODES * 4, stream);          // counts
        hist_kernel<<<(E + 255) / 256, 256, 0, stream>>>(dst, cursor, E);
        scan1_kernel<<<nScanBlocks, SCAN_TPB, 0, stream>>>(cursor, rowptr, bsum, N_NODES);
        scan2_kernel<<<1, SCAN_TPB, 0, stream>>>(bsum, nScanBlocks);
        scan3_kernel<<<(N_NODES + 255) / 256, 256, 0, stream>>>(rowptr, bsum, N_NODES, E);
        hipMemcpyAsync(cursor, rowptr, (size_t)N_NODES * 4, hipMemcpyDeviceToDevice, stream);
        reorder_kernel<<<(E + 255) / 256, 256, 0, stream>>>(src, dst, ew, cursor, ePair, E);

        // ---- layer 1 ----
        gather_kernel<<<gatherBlocks, 256, 0, stream>>>(x, rowptr, ePair, agg);
        dense_tiled<true><<<denseBlocks, 256, 0, stream>>>(agg, x, W1r, W1o, b1, out);

        // ---- layer 2 (in-place h in d_out is per-block safe) ----
        gather_kernel<<<gatherBlocks, 256, 0, stream>>>(out, rowptr, ePair, agg);
        dense_tiled<false><<<denseBlocks, 256, 0, stream>>>(agg, out, W2r, W2o, b2, out);
    } else {
        // ---- legacy atomic path (needs only agg) ----
        const int scatterBlocks = (int)(((long long)E * 64 + 255) / 256);
        hipMemsetAsync(agg, 0, aggB, stream);
        scatter_kernel<<<scatterBlocks, 256, 0, stream>>>(x, src, dst, ew, agg, E);
        dense_tiled<true><<<denseBlocks, 256, 0, stream>>>(agg, x, W1r, W1o, b1, out);
        hipMemsetAsync(agg, 0, aggB, stream);
        scatter_kernel<<<scatterBlocks, 256, 0, stream>>>(out, src, dst, ew, agg, E);
        dense_tiled<false><<<denseBlocks, 256, 0, stream>>>(agg, out, W2r, W2o, b2, out);
    }
}